// Round 4
// baseline (459.053 us; speedup 1.0000x reference)
//
#include <hip/hip_runtime.h>
#include <stdint.h>

#define BSZ 16
#define TT  2048
#define NSEM 2048
#define DIM 128
#define STRT 40   // semT row stride (elems): 80 B, 16B-aligned

typedef __attribute__((ext_vector_type(8))) short short8;
typedef __attribute__((ext_vector_type(4))) float floatx4;

__device__ __forceinline__ unsigned short f2bf(float f){       // RNE
  unsigned u = __float_as_uint(f);
  return (unsigned short)((u + 0x7fffu + ((u >> 16) & 1u)) >> 16);
}
__device__ __forceinline__ void ld8f(const float* p, float* v){
  floatx4 a = *(const floatx4*)p;
  floatx4 b = *(const floatx4*)(p + 4);
  v[0]=a[0]; v[1]=a[1]; v[2]=a[2]; v[3]=a[3];
  v[4]=b[0]; v[5]=b[1]; v[6]=b[2]; v[7]=b[3];
}

// ---------------- kernel 1: colB[b][n] = dot(sem[b][n], w2) ----------------
__global__ __launch_bounds__(256) void colB_kernel(const float* __restrict__ sem,
                                                   const float* __restrict__ W,
                                                   float* __restrict__ colB){
  int id = blockIdx.x * 256 + threadIdx.x;        // [0, BSZ*NSEM)
  const float* p = sem + (size_t)id * DIM;
  float s = 0.f;
  #pragma unroll
  for (int k = 0; k < DIM; k += 4){
    floatx4 u = *(const floatx4*)(p + k);
    floatx4 w = *(const floatx4*)(W + DIM + k);   // w2
    s += u[0]*w[0] + u[1]*w[1] + u[2]*w[2] + u[3]*w[3];
  }
  colB[id] = s;
}

// ---------------- kernel 2: flash attention over n ----------------
// grid = BSZ * (TT/64), 256 threads (4 waves x 16 t-rows).
// h (=h_con_w) -> fp32 directly into d_out segment 1; m[t] -> ws.
__global__ __launch_bounds__(256) void flash_kernel(const float* __restrict__ aud,
                                                    const float* __restrict__ sem,
                                                    const float* __restrict__ W,
                                                    const float* __restrict__ colB,
                                                    float* __restrict__ m_ws,
                                                    float* __restrict__ out){
  __shared__ alignas(16) unsigned short semT[DIM * STRT];   // bf16 sem tile [d][n], 10240 B
  __shared__ alignas(16) unsigned short pbuf[4][16 * 32];   // per-wave P staging, 4096 B

  const int tid  = threadIdx.x;
  const int wv   = tid >> 6;
  const int lane = tid & 63;
  const int quad = lane >> 4;
  const int l15  = lane & 15;
  const int bx   = blockIdx.x;
  const int b    = bx >> 5;                       // 32 blocks per batch
  const int t0   = (bx & 31) * 64 + wv * 16;      // this wave's 16 t-rows

  // ---- q A-frags (q = aud * w3 -> bf16) + rowA partial (fp32 dot aud,w1) ----
  const float* audRow = aud + ((size_t)b * TT + t0 + l15) * DIM;
  short8 qf[4];
  float rowA_part = 0.f;
  #pragma unroll
  for (int kc = 0; kc < 4; ++kc){
    int d0 = kc * 32 + quad * 8;
    float av[8], w3v[8], w1v[8];
    ld8f(audRow + d0, av);
    ld8f(W + 2 * DIM + d0, w3v);
    ld8f(W + d0, w1v);
    alignas(16) unsigned short tmp[8];
    #pragma unroll
    for (int j = 0; j < 8; ++j){
      tmp[j] = f2bf(av[j] * w3v[j]);
      rowA_part += av[j] * w1v[j];
    }
    qf[kc] = *(const short8*)tmp;
  }
  rowA_part += __shfl_xor(rowA_part, 16);
  rowA_part += __shfl_xor(rowA_part, 32);         // rowA[t0+l15] complete

  float m_run[4], l_run[4];
  floatx4 o[8];
  #pragma unroll
  for (int r = 0; r < 4; ++r){ m_run[r] = -1e30f; l_run[r] = 0.f; }
  #pragma unroll
  for (int dc = 0; dc < 8; ++dc){
    #pragma unroll
    for (int r = 0; r < 4; ++r) o[dc][r] = 0.f;
  }

  const float* semB = sem + (size_t)b * NSEM * DIM;
  const float* colBb = colB + b * NSEM;
  const int srow = tid & 31, sdc = tid >> 5;

  for (int n0 = 0; n0 < NSEM; n0 += 32){
    // stage sem tile (fp32 -> bf16) transposed into LDS for the PV MFMAs
    {
      const float* p = semB + (size_t)(n0 + srow) * DIM + sdc * 16;
      float v[16];
      ld8f(p, v); ld8f(p + 8, v + 8);
      #pragma unroll
      for (int e = 0; e < 16; ++e) semT[(sdc*16 + e) * STRT + srow] = f2bf(v[e]);
    }

    // S = q . sem^T from global (two 16x16 n-subtiles, K=128 via 4 MFMAs each)
    floatx4 s0 = {0.f,0.f,0.f,0.f}, s1 = {0.f,0.f,0.f,0.f};
    #pragma unroll
    for (int kc = 0; kc < 4; ++kc){
      int d0 = kc * 32 + quad * 8;
      float k0v[8], k1v[8];
      ld8f(semB + (size_t)(n0 + l15)      * DIM + d0, k0v);
      ld8f(semB + (size_t)(n0 + 16 + l15) * DIM + d0, k1v);
      alignas(16) unsigned short tk0[8], tk1[8];
      #pragma unroll
      for (int j = 0; j < 8; ++j){ tk0[j] = f2bf(k0v[j]); tk1[j] = f2bf(k1v[j]); }
      s0 = __builtin_amdgcn_mfma_f32_16x16x32_bf16(qf[kc], *(const short8*)tk0, s0, 0, 0, 0);
      s1 = __builtin_amdgcn_mfma_f32_16x16x32_bf16(qf[kc], *(const short8*)tk1, s1, 0, 0, 0);
    }

    // online softmax over n (rows t = quad*4+r, cols n = l15 / 16+l15)
    float cb0 = colBb[n0 + l15];
    float cb1 = colBb[n0 + 16 + l15];
    float p0[4], p1[4], alpha[4];
    #pragma unroll
    for (int r = 0; r < 4; ++r){
      float v0 = s0[r] + cb0;
      float v1 = s1[r] + cb1;
      float mx = fmaxf(v0, v1);
      mx = fmaxf(mx, __shfl_xor(mx, 1));
      mx = fmaxf(mx, __shfl_xor(mx, 2));
      mx = fmaxf(mx, __shfl_xor(mx, 4));
      mx = fmaxf(mx, __shfl_xor(mx, 8));
      float mnew = fmaxf(m_run[r], mx);
      float al = __expf(m_run[r] - mnew);
      m_run[r] = mnew; alpha[r] = al;
      float e0 = __expf(v0 - mnew);
      float e1 = __expf(v1 - mnew);
      float ps = e0 + e1;
      ps += __shfl_xor(ps, 1);
      ps += __shfl_xor(ps, 2);
      ps += __shfl_xor(ps, 4);
      ps += __shfl_xor(ps, 8);
      l_run[r] = l_run[r] * al + ps;
      p0[r] = e0; p1[r] = e1;
    }
    #pragma unroll
    for (int dc = 0; dc < 8; ++dc){
      #pragma unroll
      for (int r = 0; r < 4; ++r) o[dc][r] *= alpha[r];
    }

    // P: C-layout -> A-layout staging (visibility via the barrier below)
    #pragma unroll
    for (int r = 0; r < 4; ++r){
      pbuf[wv][(quad*4 + r)*32 + l15]      = f2bf(p0[r]);
      pbuf[wv][(quad*4 + r)*32 + 16 + l15] = f2bf(p1[r]);
    }
    __syncthreads();   // semT + pbuf visible

    short8 pf = *(const short8*)&pbuf[wv][l15*32 + quad*8];
    #pragma unroll
    for (int dc = 0; dc < 8; ++dc){
      short8 vf = *(const short8*)&semT[(dc*16 + l15) * STRT + quad*8];
      o[dc] = __builtin_amdgcn_mfma_f32_16x16x32_bf16(pf, vf, o[dc], 0, 0, 0);
    }
    __syncthreads();   // protect semT/pbuf before next overwrite
  }

  // epilogue: h = O / l -> out seg1 (fp32);  m[t] = max + rowA[t] -> ws
  float rl[4];
  #pragma unroll
  for (int r = 0; r < 4; ++r) rl[r] = 1.0f / l_run[r];
  float* outB = out + ((size_t)b * TT + t0) * 512 + 128;   // seg1
  #pragma unroll
  for (int dc = 0; dc < 8; ++dc){
    #pragma unroll
    for (int r = 0; r < 4; ++r)
      outB[(size_t)(quad*4 + r) * 512 + dc*16 + l15] = o[dc][r] * rl[r];
  }
  float rAr[4];
  #pragma unroll
  for (int r = 0; r < 4; ++r) rAr[r] = __shfl(rowA_part, quad*4 + r);  // before divergence
  if (l15 == 0){
    #pragma unroll
    for (int r = 0; r < 4; ++r)
      m_ws[(size_t)b * TT + t0 + quad*4 + r] = m_run[r] + rAr[r];
  }
}

// ---------------- kernel 3: bw = softmax_t(m); a2[b][d] = sum_t bw*aud ----------------
__global__ __launch_bounds__(1024) void bw_kernel(const float* __restrict__ aud,
                                                  const float* __restrict__ m_ws,
                                                  float* __restrict__ a2_ws){
  __shared__ float pbw[TT];          // 8 KB
  __shared__ float red[64 * DIM];    // 32 KB
  __shared__ float sredA[16], sredB[16];
  const int b = blockIdx.x, tid = threadIdx.x;

  float v0 = m_ws[(size_t)b * TT + tid];
  float v1 = m_ws[(size_t)b * TT + 1024 + tid];
  float mx = fmaxf(v0, v1);
  #pragma unroll
  for (int off = 1; off < 64; off <<= 1) mx = fmaxf(mx, __shfl_xor(mx, off));
  if ((tid & 63) == 0) sredA[tid >> 6] = mx;
  __syncthreads();
  float gmax = sredA[0];
  #pragma unroll
  for (int i = 1; i < 16; ++i) gmax = fmaxf(gmax, sredA[i]);

  float e0 = __expf(v0 - gmax), e1 = __expf(v1 - gmax);
  pbw[tid] = e0; pbw[tid + 1024] = e1;
  float sm = e0 + e1;
  #pragma unroll
  for (int off = 1; off < 64; off <<= 1) sm += __shfl_xor(sm, off);
  if ((tid & 63) == 0) sredB[tid >> 6] = sm;
  __syncthreads();
  float gsum = 0.f;
  #pragma unroll
  for (int i = 0; i < 16; ++i) gsum += sredB[i];
  float inv = 1.0f / gsum;

  // a2: thread (dg = tid&15 -> 8 d's, q = tid>>4 -> 32 t's)
  const int dg = tid & 15, q = tid >> 4;
  float acc[8] = {0,0,0,0,0,0,0,0};
  const float* ab = aud + (size_t)b * TT * DIM;
  for (int tt = 0; tt < 32; ++tt){
    int t = q * 32 + tt;
    float av[8];
    ld8f(ab + (size_t)t * DIM + dg * 8, av);
    float w = pbw[t];
    #pragma unroll
    for (int j = 0; j < 8; ++j) acc[j] += w * av[j];
  }
  #pragma unroll
  for (int j = 0; j < 8; ++j) red[q * DIM + dg * 8 + j] = acc[j];
  __syncthreads();
  if (tid < DIM){
    float s = 0.f;
    for (int q2 = 0; q2 < 64; ++q2) s += red[q2 * DIM + tid];
    a2_ws[b * DIM + tid] = s * inv;
  }
}

// ---------------- kernel 4: read seg1 (h), write seg0/2/3 ----------------
__global__ __launch_bounds__(256) void epi_kernel(const float* __restrict__ aud,
                                                  const float* __restrict__ a2_ws,
                                                  float* __restrict__ out){
  int id = blockIdx.x * 256 + threadIdx.x;        // BSZ*TT*16
  int c = id & 15;
  int t = (id >> 4) & (TT - 1);
  int b = id >> 15;
  size_t row = (size_t)b * TT + t;

  float av[8], gv[8], hv[8];
  ld8f(aud + row * DIM + c * 8, av);
  ld8f(a2_ws + b * DIM + c * 8, gv);
  ld8f(out + row * 512 + 128 + c * 8, hv);        // h (seg1, fp32, written by flash)

  floatx4 o0a, o0b, o2a, o2b, o3a, o3b;
  #pragma unroll
  for (int j = 0; j < 4; ++j){
    o0a[j] = av[j];           o0b[j] = av[4+j];
    o2a[j] = av[j]*hv[j];     o2b[j] = av[4+j]*hv[4+j];
    o3a[j] = av[j]*gv[j];     o3b[j] = av[4+j]*gv[4+j];
  }
  float* ob = out + row * 512 + c * 8;
  *(floatx4*)(ob)           = o0a;  *(floatx4*)(ob + 4)       = o0b;   // seg0: aud
  *(floatx4*)(ob + 256)     = o2a;  *(floatx4*)(ob + 260)     = o2b;   // seg2: aud*h
  *(floatx4*)(ob + 384)     = o3a;  *(floatx4*)(ob + 388)     = o3b;   // seg3: aud*a2
}

extern "C" void kernel_launch(void* const* d_in, const int* in_sizes, int n_in,
                              void* d_out, int out_size, void* d_ws, size_t ws_size,
                              hipStream_t stream){
  const float* aud = (const float*)d_in[0];   // fp32 (confirmed: bf16 read gave NaN)
  const float* sem = (const float*)d_in[1];
  const float* W   = (const float*)d_in[2];
  // d_in[3] (bias b) provably cancels in both softmaxes and never reaches the output.
  float* out = (float*)d_out;                 // fp32 (error-signature evidence, round 3)

  // ws usage: 264 KB total
  float* ws    = (float*)d_ws;
  float* m_ws  = ws;                                   // BSZ*TT      (128 KB)
  float* colB  = m_ws + (size_t)BSZ * TT;              // BSZ*NSEM    (128 KB)
  float* a2_ws = colB + (size_t)BSZ * NSEM;            // BSZ*DIM     (8 KB)

  colB_kernel<<<(BSZ * NSEM) / 256, 256, 0, stream>>>(sem, W, colB);
  flash_kernel<<<BSZ * (TT / 64), 256, 0, stream>>>(aud, sem, W, colB, m_ws, out);
  bw_kernel<<<BSZ, 1024, 0, stream>>>(aud, m_ws, a2_ws);
  epi_kernel<<<(BSZ * TT * 16) / 256, 256, 0, stream>>>(aud, a2_ws, out);
}

// Round 5
// 346.884 us; speedup vs baseline: 1.3234x; 1.3234x over previous
//
#include <hip/hip_runtime.h>
#include <stdint.h>

#define BSZ 16
#define TT  2048
#define NSEM 2048
#define DIM 128
#define ORS 1024          // shorts per output row (512 floats)
#define PSTR 68           // pbuf row stride in shorts

typedef __attribute__((ext_vector_type(8))) short short8;
typedef __attribute__((ext_vector_type(4))) float floatx4;

__device__ __forceinline__ unsigned short f2bf(float f){       // RNE
  unsigned u = __float_as_uint(f);
  return (unsigned short)((u + 0x7fffu + ((u >> 16) & 1u)) >> 16);
}
__device__ __forceinline__ void ld8f(const float* p, float* v){
  floatx4 a = *(const floatx4*)p;
  floatx4 b = *(const floatx4*)(p + 4);
  v[0]=a[0]; v[1]=a[1]; v[2]=a[2]; v[3]=a[3];
  v[4]=b[0]; v[5]=b[1]; v[6]=b[2]; v[7]=b[3];
}

// ---------------- kernel 1: prep ----------------
// grid 512 (b = bx>>5, n0 = (bx&31)*64), 256 thr.
// Writes semBF (bf16 [b][n][d]) into out seg0 shorts[0,128); semT (bf16 [b][d][n])
// into out rows b*TT + d*4+piece, shorts [512,1024); colB -> ws.
__global__ __launch_bounds__(256) void prep_kernel(const float* __restrict__ sem,
                                                   const float* __restrict__ W,
                                                   float* __restrict__ colB,
                                                   unsigned short* __restrict__ outw){
  __shared__ unsigned short tile[DIM * 72];        // [d][n] bf16, stride 72 (144B, 16B-mult)
  const int tid = threadIdx.x;
  const int b  = blockIdx.x >> 5;
  const int n0 = (blockIdx.x & 31) * 64;

  // phase 1: row r (64 rows), col chunk c (32 cols)
  const int r = tid >> 2, cc = tid & 3, c = cc * 32;
  const float* src = sem + ((size_t)(b * NSEM + n0 + r)) * DIM + c;
  float v[32];
  ld8f(src, v); ld8f(src + 8, v + 8); ld8f(src + 16, v + 16); ld8f(src + 24, v + 24);
  alignas(16) unsigned short bf[32];
  float cpart = 0.f;
  #pragma unroll
  for (int j = 0; j < 32; ++j){
    bf[j] = f2bf(v[j]);
    cpart += v[j] * W[DIM + c + j];                // w2 dot partial
  }
  // semBF write (seg0): 64B contiguous
  {
    unsigned short* dst = outw + ((size_t)(b * TT + n0 + r)) * ORS + c;
    const uint4* s4 = (const uint4*)bf;
    *(uint4*)(dst) = s4[0]; *(uint4*)(dst+8) = s4[1];
    *(uint4*)(dst+16) = s4[2]; *(uint4*)(dst+24) = s4[3];
  }
  // LDS transpose stage
  #pragma unroll
  for (int j = 0; j < 32; ++j) tile[(c + j) * 72 + r] = bf[j];
  // colB reduce over the 4 col-chunks (lanes differing in bits 0..1)
  cpart += __shfl_xor(cpart, 1);
  cpart += __shfl_xor(cpart, 2);
  if (cc == 0) colB[b * NSEM + n0 + r] = cpart;
  __syncthreads();

  // phase 2: semT write. d = tid>>1 (128), nh = (tid&1)*32
  const int d = tid >> 1, nh = (tid & 1) * 32;
  uint4 t0v = *(const uint4*)&tile[d * 72 + nh];
  uint4 t1v = *(const uint4*)&tile[d * 72 + nh + 8];
  uint4 t2v = *(const uint4*)&tile[d * 72 + nh + 16];
  uint4 t3v = *(const uint4*)&tile[d * 72 + nh + 24];
  const int n = n0 + nh;
  const int piece = n >> 9;
  unsigned short* dst = outw + ((size_t)(b * TT + d * 4 + piece)) * ORS + 512 + (n & 511);
  *(uint4*)(dst) = t0v; *(uint4*)(dst+8) = t1v;
  *(uint4*)(dst+16) = t2v; *(uint4*)(dst+24) = t3v;
}

// ---------------- kernel 2: flash attention over n ----------------
// grid 512 (b = bx>>5, t-block), 256 thr (4 waves x 16 t-rows). No block barriers in loop.
__global__ __launch_bounds__(256) void flash_kernel(const float* __restrict__ aud,
                                                    const float* __restrict__ W,
                                                    const float* __restrict__ colB,
                                                    float* __restrict__ m_ws,
                                                    float* __restrict__ outf,
                                                    const unsigned short* __restrict__ outw){
  __shared__ alignas(16) unsigned short pbuf[4][16 * PSTR];   // per-wave P staging, 8704 B

  const int tid  = threadIdx.x;
  const int wv   = tid >> 6;
  const int lane = tid & 63;
  const int quad = lane >> 4;
  const int l15  = lane & 15;
  const int b    = blockIdx.x >> 5;
  const int t0   = (blockIdx.x & 31) * 64 + wv * 16;

  // q A-frags (aud*w3 -> bf16) + rowA partial (fp32 dot aud,w1)
  const float* audRow = aud + ((size_t)b * TT + t0 + l15) * DIM;
  short8 qf[4];
  float rowA_part = 0.f;
  #pragma unroll
  for (int kc = 0; kc < 4; ++kc){
    int d0 = kc * 32 + quad * 8;
    float av[8], w3v[8], w1v[8];
    ld8f(audRow + d0, av);
    ld8f(W + 2 * DIM + d0, w3v);
    ld8f(W + d0, w1v);
    alignas(16) unsigned short tmp[8];
    #pragma unroll
    for (int j = 0; j < 8; ++j){
      tmp[j] = f2bf(av[j] * w3v[j]);
      rowA_part += av[j] * w1v[j];
    }
    qf[kc] = *(const short8*)tmp;
  }
  rowA_part += __shfl_xor(rowA_part, 16);
  rowA_part += __shfl_xor(rowA_part, 32);

  float m_run[4], l_run[4];
  floatx4 o[8];
  #pragma unroll
  for (int r = 0; r < 4; ++r){ m_run[r] = -1e30f; l_run[r] = 0.f; }
  #pragma unroll
  for (int dc = 0; dc < 8; ++dc){
    #pragma unroll
    for (int r = 0; r < 4; ++r) o[dc][r] = 0.f;
  }

  const unsigned short* semBF = outw + (size_t)b * TT * ORS;   // row n -> shorts [0,128)
  const float* colBb = colB + b * NSEM;
  unsigned short* pb = &pbuf[wv][0];

  for (int n0 = 0; n0 < NSEM; n0 += 64){
    // ---- QK: S = q . sem^T, 4 subtiles of 16 n ----
    floatx4 sacc[4];
    #pragma unroll
    for (int s = 0; s < 4; ++s){ sacc[s][0]=0.f; sacc[s][1]=0.f; sacc[s][2]=0.f; sacc[s][3]=0.f; }
    #pragma unroll
    for (int s = 0; s < 4; ++s){
      const unsigned short* kr = semBF + (size_t)(n0 + s*16 + l15) * ORS + quad * 8;
      #pragma unroll
      for (int kc = 0; kc < 4; ++kc){
        short8 kf = *(const short8*)(kr + kc * 32);
        sacc[s] = __builtin_amdgcn_mfma_f32_16x16x32_bf16(qf[kc], kf, sacc[s], 0, 0, 0);
      }
    }

    // ---- online softmax over 64 n ----
    float cb[4];
    #pragma unroll
    for (int s = 0; s < 4; ++s) cb[s] = colBb[n0 + s*16 + l15];
    float alpha[4];
    #pragma unroll
    for (int r = 0; r < 4; ++r){
      float v0 = sacc[0][r] + cb[0];
      float v1 = sacc[1][r] + cb[1];
      float v2 = sacc[2][r] + cb[2];
      float v3 = sacc[3][r] + cb[3];
      float mx = fmaxf(fmaxf(v0, v1), fmaxf(v2, v3));
      mx = fmaxf(mx, __shfl_xor(mx, 1));
      mx = fmaxf(mx, __shfl_xor(mx, 2));
      mx = fmaxf(mx, __shfl_xor(mx, 4));
      mx = fmaxf(mx, __shfl_xor(mx, 8));
      float mnew = fmaxf(m_run[r], mx);
      float al = __expf(m_run[r] - mnew);
      m_run[r] = mnew; alpha[r] = al;
      float e0 = __expf(v0 - mnew), e1 = __expf(v1 - mnew);
      float e2 = __expf(v2 - mnew), e3 = __expf(v3 - mnew);
      float ps = (e0 + e1) + (e2 + e3);
      ps += __shfl_xor(ps, 1);
      ps += __shfl_xor(ps, 2);
      ps += __shfl_xor(ps, 4);
      ps += __shfl_xor(ps, 8);
      l_run[r] = l_run[r] * al + ps;
      // P staging (wave-private)
      unsigned short* pr = pb + (quad*4 + r) * PSTR;
      pr[l15]      = f2bf(e0);
      pr[16 + l15] = f2bf(e1);
      pr[32 + l15] = f2bf(e2);
      pr[48 + l15] = f2bf(e3);
    }
    #pragma unroll
    for (int dc = 0; dc < 8; ++dc){
      #pragma unroll
      for (int r = 0; r < 4; ++r) o[dc][r] *= alpha[r];
    }

    // wave-local LDS visibility (in-order DS per wave; just drain writes)
    asm volatile("s_waitcnt lgkmcnt(0)" ::: "memory");
    short8 pf0 = *(const short8*)(pb + l15 * PSTR + quad * 8);
    short8 pf1 = *(const short8*)(pb + l15 * PSTR + 32 + quad * 8);

    // ---- PV: O += P . sem, B-frags direct from semT scratch ----
    #pragma unroll
    for (int kt = 0; kt < 2; ++kt){
      short8 pf = kt ? pf1 : pf0;
      int n = n0 + kt * 32 + quad * 8;
      int piece = n >> 9, nin = n & 511;
      #pragma unroll
      for (int dc = 0; dc < 8; ++dc){
        const unsigned short* vp = outw +
          ((size_t)(b * TT + (dc*16 + l15) * 4 + piece)) * ORS + 512 + nin;
        short8 vf = *(const short8*)vp;
        o[dc] = __builtin_amdgcn_mfma_f32_16x16x32_bf16(pf, vf, o[dc], 0, 0, 0);
      }
    }
  }

  // epilogue: h = O/l -> out seg1 (fp32); m -> ws
  float rl[4];
  #pragma unroll
  for (int r = 0; r < 4; ++r) rl[r] = 1.0f / l_run[r];
  float* outB = outf + ((size_t)b * TT + t0) * 512 + 128;
  #pragma unroll
  for (int dc = 0; dc < 8; ++dc){
    #pragma unroll
    for (int r = 0; r < 4; ++r)
      outB[(size_t)(quad*4 + r) * 512 + dc*16 + l15] = o[dc][r] * rl[r];
  }
  float rAr[4];
  #pragma unroll
  for (int r = 0; r < 4; ++r) rAr[r] = __shfl(rowA_part, quad*4 + r);
  if (l15 == 0){
    #pragma unroll
    for (int r = 0; r < 4; ++r)
      m_ws[(size_t)b * TT + t0 + quad*4 + r] = m_run[r] + rAr[r];
  }
}

// ---------------- kernel 3a: per-chunk max of m ----------------
__global__ __launch_bounds__(256) void bw1_kernel(const float* __restrict__ m_ws,
                                                  float* __restrict__ pmax){
  __shared__ float sA[4];
  const int b = blockIdx.x >> 3, ch = blockIdx.x & 7, tid = threadIdx.x;
  float v = m_ws[(size_t)b * TT + ch * 256 + tid];
  #pragma unroll
  for (int off = 1; off < 64; off <<= 1) v = fmaxf(v, __shfl_xor(v, off));
  if ((tid & 63) == 0) sA[tid >> 6] = v;
  __syncthreads();
  if (tid == 0)
    pmax[blockIdx.x] = fmaxf(fmaxf(sA[0], sA[1]), fmaxf(sA[2], sA[3]));
}

// ---------------- kernel 3b: partial exp-sum + partial a2 ----------------
__global__ __launch_bounds__(256) void bw2_kernel(const float* __restrict__ aud,
                                                  const float* __restrict__ m_ws,
                                                  const float* __restrict__ pmax,
                                                  float* __restrict__ gpart,
                                                  float* __restrict__ part){
  __shared__ float wbuf[256];
  __shared__ float red[16 * 128];
  __shared__ float gs4[4];
  const int b = blockIdx.x >> 3, ch = blockIdx.x & 7, tid = threadIdx.x;

  float gmax = pmax[b * 8];
  #pragma unroll
  for (int i = 1; i < 8; ++i) gmax = fmaxf(gmax, pmax[b * 8 + i]);

  float w = __expf(m_ws[(size_t)b * TT + ch * 256 + tid] - gmax);
  wbuf[tid] = w;
  float sm = w;
  #pragma unroll
  for (int off = 1; off < 64; off <<= 1) sm += __shfl_xor(sm, off);
  if ((tid & 63) == 0) gs4[tid >> 6] = sm;
  __syncthreads();
  if (tid == 0) gpart[blockIdx.x] = (gs4[0] + gs4[1]) + (gs4[2] + gs4[3]);

  const int dg = tid & 15, q = tid >> 4;
  float acc[8] = {0,0,0,0,0,0,0,0};
  const float* ab = aud + ((size_t)b * TT + ch * 256 + q * 16) * DIM + dg * 8;
  for (int i = 0; i < 16; ++i){
    float av[8];
    ld8f(ab + (size_t)i * DIM, av);
    float wt = wbuf[q * 16 + i];
    #pragma unroll
    for (int j = 0; j < 8; ++j) acc[j] += wt * av[j];
  }
  #pragma unroll
  for (int j = 0; j < 8; ++j) red[q * 128 + dg * 8 + j] = acc[j];
  __syncthreads();
  if (tid < 128){
    float s = 0.f;
    #pragma unroll
    for (int q2 = 0; q2 < 16; ++q2) s += red[q2 * 128 + tid];
    part[(size_t)blockIdx.x * 128 + tid] = s;
  }
}

// ---------------- kernel 3c: combine partials -> normalized a2 ----------------
__global__ __launch_bounds__(128) void bw3_kernel(const float* __restrict__ gpart,
                                                  const float* __restrict__ part,
                                                  float* __restrict__ a2_ws){
  const int b = blockIdx.x, d = threadIdx.x;
  float s = 0.f, g = 0.f;
  #pragma unroll
  for (int ch = 0; ch < 8; ++ch){
    s += part[(size_t)(b * 8 + ch) * 128 + d];
    g += gpart[b * 8 + ch];
  }
  a2_ws[b * DIM + d] = s / g;
}

// ---------------- kernel 4: read seg1 (h), write seg0/2/3 ----------------
__global__ __launch_bounds__(256) void epi_kernel(const float* __restrict__ aud,
                                                  const float* __restrict__ a2_ws,
                                                  float* __restrict__ out){
  int id = blockIdx.x * 256 + threadIdx.x;        // BSZ*TT*16
  int c = id & 15;
  int t = (id >> 4) & (TT - 1);
  int b = id >> 15;
  size_t row = (size_t)b * TT + t;

  float av[8], gv[8], hv[8];
  ld8f(aud + row * DIM + c * 8, av);
  ld8f(a2_ws + b * DIM + c * 8, gv);
  ld8f(out + row * 512 + 128 + c * 8, hv);        // h (seg1)

  floatx4 o0a, o0b, o2a, o2b, o3a, o3b;
  #pragma unroll
  for (int j = 0; j < 4; ++j){
    o0a[j] = av[j];           o0b[j] = av[4+j];
    o2a[j] = av[j]*hv[j];     o2b[j] = av[4+j]*hv[4+j];
    o3a[j] = av[j]*gv[j];     o3b[j] = av[4+j]*gv[4+j];
  }
  float* ob = out + row * 512 + c * 8;
  *(floatx4*)(ob)       = o0a;  *(floatx4*)(ob + 4)   = o0b;   // seg0: aud
  *(floatx4*)(ob + 256) = o2a;  *(floatx4*)(ob + 260) = o2b;   // seg2: aud*h
  *(floatx4*)(ob + 384) = o3a;  *(floatx4*)(ob + 388) = o3b;   // seg3: aud*a2
}

extern "C" void kernel_launch(void* const* d_in, const int* in_sizes, int n_in,
                              void* d_out, int out_size, void* d_ws, size_t ws_size,
                              hipStream_t stream){
  const float* aud = (const float*)d_in[0];   // fp32 inputs (verified round 4)
  const float* sem = (const float*)d_in[1];
  const float* W   = (const float*)d_in[2];
  // d_in[3] (bias) cancels in both softmaxes.
  float* out = (float*)d_out;                 // fp32 output (verified round 4)
  unsigned short* outw = (unsigned short*)d_out;

  // ws: ~329 KB
  float* ws    = (float*)d_ws;
  float* m_ws  = ws;                                   // 32768 f (128 KB)
  float* colB  = m_ws + (size_t)BSZ * TT;              // 32768 f (128 KB)
  float* a2_ws = colB + (size_t)BSZ * NSEM;            // 2048 f  (8 KB)
  float* pmax  = a2_ws + BSZ * DIM;                    // 128 f
  float* gpart = pmax + 128;                           // 128 f
  float* part  = gpart + 128;                          // 16384 f (64 KB)

  prep_kernel <<<512, 256, 0, stream>>>(sem, W, colB, outw);
  flash_kernel<<<512, 256, 0, stream>>>(aud, W, colB, m_ws, out, outw);
  bw1_kernel  <<<128, 256, 0, stream>>>(m_ws, pmax);
  bw2_kernel  <<<128, 256, 0, stream>>>(aud, m_ws, pmax, gpart, part);
  bw3_kernel  <<<BSZ, 128, 0, stream>>>(gpart, part, a2_ws);
  epi_kernel  <<<(BSZ * TT * 16) / 256, 256, 0, stream>>>(aud, a2_ws, out);
}